// Round 1
// baseline (122.124 us; speedup 1.0000x reference)
//
#include <hip/hip_runtime.h>

#define B_TOT 4096

// One WAVE per batch: 4 independent waves per 256-thread block, zero __syncthreads.
// Lane L, step j covers grid elements [256j + 4L .. +3]  (1 KiB coalesced per wave-load).
// row = 4j + (L>>4)  (16 consecutive lanes share a row), cols c0=(L&15)*4 .. c0+3.
__global__ __launch_bounds__(256) void energy_kernel(
    const float* __restrict__ grid,
    const float* __restrict__ hints,
    const float* __restrict__ w_g,
    const float* __restrict__ w_h,
    float* __restrict__ ws)
{
    const int tid  = threadIdx.x;
    const int lane = tid & 63;
    const int wv   = tid >> 6;
    const int b    = (blockIdx.x << 2) + wv;

    // Per-wave private target slices -> no barrier needed (intra-wave lgkmcnt ordering).
    __shared__ __align__(16) float tgt[4][2][64];

    const float* hb = hints + (size_t)b * 2048;
    const float* gb = grid  + (size_t)b * 4096;

    float neural = 0.f;

    // ---- Phase A: hints. 8 coalesced float4 per lane; hint-row = 16j + (L>>2),
    // each 4-lane group holds one full 16-elem hint row.
    #pragma unroll
    for (int j = 0; j < 8; ++j) {
        float4 h  = *(const float4*)(hb  + 256 * j + 4 * lane);
        float4 wh = *(const float4*)(w_h + 256 * j + 4 * lane);
        neural += h.x * wh.x + h.y * wh.y + h.z * wh.z + h.w * wh.w;
        float s = h.x + h.y + h.z + h.w;
        s += __shfl_xor(s, 1);
        s += __shfl_xor(s, 2);
        if ((lane & 3) == 0) {
            int r = 16 * j + (lane >> 2);        // 0..127: [0..63]=row tgt, [64..127]=col tgt
            tgt[wv][r >> 6][r & 63] = s;
        }
    }

    // ---- Phase B: size (ballot is wave-uniform; LDS write->read same wave, no barrier).
    unsigned long long mr = __ballot(tgt[wv][0][lane] > 0.f);
    unsigned long long mc = __ballot(tgt[wv][1][lane] > 0.f);
    int lr = mr ? (63 - __builtin_clzll(mr)) : -1;
    int lc = mc ? (63 - __builtin_clzll(mc)) : -1;
    const int   size = (lr >= 0 && lc >= 0) ? (max(lr, lc) + 1) : 12;  // FALLBACK
    const float sz   = (float)size;

    const int c0 = (lane & 15) << 2;
    const float mx = (c0 + 0 < size) ? 1.f : 0.f;
    const float my = (c0 + 1 < size) ? 1.f : 0.f;
    const float mz = (c0 + 2 < size) ? 1.f : 0.f;
    const float mw = (c0 + 3 < size) ? 1.f : 0.f;
    const float lm0 = ((lane & 15) == 0) ? 1.f : 0.f;   // one accumulator lane per row

    float binp = 0.f, errp = 0.f;
    float4 cacc = {0.f, 0.f, 0.f, 0.f};

    // ---- Phase C: grid. unroll 4 = 8 loads in flight without VGPR blowup.
    #pragma unroll 4
    for (int j = 0; j < 16; ++j) {
        float4 g = *(const float4*)(gb  + 256 * j + 4 * lane);
        float4 w = *(const float4*)(w_g + 256 * j + 4 * lane);   // L1-resident (16 KiB, shared by all waves)
        neural += g.x * w.x + g.y * w.y + g.z * w.z + g.w * w.w;

        const int   row   = 4 * j + (lane >> 4);
        const float rmask = (row < size) ? 1.f : 0.f;
        binp += rmask * (mx * g.x * g.x + my * g.y * g.y + mz * g.z * g.z + mw * g.w * g.w);

        // sigmoid(3g) via v_exp + v_rcp (accuracy irrelevant at threshold)
        float sx = __builtin_amdgcn_rcpf(1.f + __expf(-3.f * g.x));
        float sy = __builtin_amdgcn_rcpf(1.f + __expf(-3.f * g.y));
        float s2 = __builtin_amdgcn_rcpf(1.f + __expf(-3.f * g.z));
        float sw = __builtin_amdgcn_rcpf(1.f + __expf(-3.f * g.w));

        // row sum across the 16 lanes sharing this row
        float rs = mx * sx + my * sy + mz * s2 + mw * sw;
        rs += __shfl_xor(rs, 1);
        rs += __shfl_xor(rs, 2);
        rs += __shfl_xor(rs, 4);
        rs += __shfl_xor(rs, 8);
        float d = rs - tgt[wv][0][row];          // broadcast read (16 lanes same addr)
        errp += lm0 * rmask * d * d;

        cacc.x += rmask * sx;
        cacc.y += rmask * sy;
        cacc.z += rmask * s2;
        cacc.w += rmask * sw;
    }

    // column partials: sum the 4 row-groups (stride-16 lanes) in-register
    cacc.x += __shfl_xor(cacc.x, 16); cacc.x += __shfl_xor(cacc.x, 32);
    cacc.y += __shfl_xor(cacc.y, 16); cacc.y += __shfl_xor(cacc.y, 32);
    cacc.z += __shfl_xor(cacc.z, 16); cacc.z += __shfl_xor(cacc.z, 32);
    cacc.w += __shfl_xor(cacc.w, 16); cacc.w += __shfl_xor(cacc.w, 32);

    if (lane < 16) {            // lanes 0..15 own column quads 4L..4L+3
        float4 t = *(const float4*)&tgt[wv][1][c0];
        float dx = cacc.x - t.x, dy = cacc.y - t.y, dz = cacc.z - t.z, dw = cacc.w - t.w;
        errp += mx * dx * dx + my * dy * dy + mz * dz * dz + mw * dw * dw;
    }

    // ---- combine + wave reduce -> one partial per batch
    float v = neural + errp * (10.f / sz) + binp * (0.1f / (sz * sz));
    #pragma unroll
    for (int off = 1; off < 64; off <<= 1) v += __shfl_xor(v, off);
    if (lane == 0) ws[b] = v;
}

__global__ __launch_bounds__(1024) void final_reduce_kernel(
    const float* __restrict__ ws, float* __restrict__ out)
{
    const int tid = threadIdx.x;
    float4 v4 = ((const float4*)ws)[tid];       // 4096 floats / 1024 threads
    float v = v4.x + v4.y + v4.z + v4.w;
    #pragma unroll
    for (int off = 1; off < 64; off <<= 1) v += __shfl_xor(v, off);
    __shared__ float r[16];
    if ((tid & 63) == 0) r[tid >> 6] = v;
    __syncthreads();
    if (tid < 16) {
        float t = r[tid];
        t += __shfl_xor(t, 1);
        t += __shfl_xor(t, 2);
        t += __shfl_xor(t, 4);
        t += __shfl_xor(t, 8);
        if (tid == 0) out[0] = t * (1.f / (float)B_TOT);
    }
}

extern "C" void kernel_launch(void* const* d_in, const int* in_sizes, int n_in,
                              void* d_out, int out_size, void* d_ws, size_t ws_size,
                              hipStream_t stream) {
    const float* grid_p  = (const float*)d_in[0];
    const float* hints_p = (const float*)d_in[1];
    const float* w_g     = (const float*)d_in[2];
    const float* w_h     = (const float*)d_in[3];
    float* out = (float*)d_out;
    float* ws  = (float*)d_ws;

    energy_kernel<<<B_TOT / 4, 256, 0, stream>>>(grid_p, hints_p, w_g, w_h, ws);
    final_reduce_kernel<<<1, 1024, 0, stream>>>(ws, out);
}